// Round 11
// baseline (206.330 us; speedup 1.0000x reference)
//
#include <hip/hip_runtime.h>

#define N_NODES 100000
#define N_EDGES 1600000
#define D_IN    128
#define D_OUT   256
#define NB_SCAN ((N_NODES + 255) / 256)
#define BLK_ROWS 64
#define N_TILES  ((N_NODES + BLK_ROWS - 1) / BLK_ROWS)   // 1563
#define X_ROWS   (N_TILES * BLK_ROWS)                    // 100032 (padded)

#define NBUCK      98                     // ceil(100000 / 1024) coarse buckets
#define BCAP       20480                  // slack: mean 16327, sigma ~127
#define BIN_CHUNK  1024
#define BIN_BLOCKS ((N_EDGES + BIN_CHUNK - 1) / BIN_CHUNK)   // 1563

typedef __attribute__((ext_vector_type(8))) short short8v;   // 8 bf16 (4 VGPRs)
typedef __attribute__((ext_vector_type(4))) float f32x4;

// ---------------------------------------------------------------------------
// bf16 helpers (RNE)
// ---------------------------------------------------------------------------
__device__ __forceinline__ unsigned bf16_rn(float f) {
    unsigned u = __float_as_uint(f);
    return (u + 0x7FFFu + ((u >> 16) & 1u)) >> 16;
}
__device__ __forceinline__ unsigned pack2_bf16(float a, float b) {
    return bf16_rn(a) | (bf16_rn(b) << 16);
}

// ---------------------------------------------------------------------------
// Detect int64 vs int32 edge_index; also zeros bucket_alloc (saves a memset
// dispatch). 128 threads.
// ---------------------------------------------------------------------------
__global__ void detect_idx64_kernel(const int* __restrict__ edge32,
                                    int* __restrict__ flag,
                                    int* __restrict__ balloc) {
    const int t = threadIdx.x;
    if (t < 128) balloc[t] = 0;
    if (t == 0 && blockIdx.x == 0) {
        int is64 = 1;
        for (int i = 1; i < 32; i += 2) {
            if (edge32[i] != 0) { is64 = 0; break; }
        }
        *flag = is64;
    }
}

__device__ __forceinline__ int load_dst(const void* edge_raw, int is64, int e) {
    if (is64) return (int)((const long long*)edge_raw)[(long long)N_EDGES + e];
    return ((const int*)edge_raw)[N_EDGES + e];
}
__device__ __forceinline__ int load_src(const void* edge_raw, int is64, int e) {
    if (is64) return (int)((const long long*)edge_raw)[e];
    return ((const int*)edge_raw)[e];
}

// ---------------------------------------------------------------------------
// H f32 -> bf16 (packed pairs)
// ---------------------------------------------------------------------------
__global__ __launch_bounds__(256) void cvt_h_kernel(
        const float* __restrict__ H, unsigned* __restrict__ Hb) {
    int i = blockIdx.x * 256 + threadIdx.x;
    if (i >= N_NODES * (D_IN / 2)) return;
    const float2 h = ((const float2*)H)[i];
    Hb[i] = pack2_bf16(h.x, h.y);
}

// ---------------------------------------------------------------------------
// Pack W into bf16 MFMA B-fragments (R6-proven layout)
// ---------------------------------------------------------------------------
__global__ __launch_bounds__(256) void pack_w_kernel(
        const float* __restrict__ W, unsigned short* __restrict__ Wp) {
    int t = blockIdx.x * 256 + threadIdx.x;   // 0..4095
    if (t >= 64 * 64) return;
    const int f  = t >> 6;
    const int l  = t & 63;
    const int nb = f >> 2;
    const int ks = f & 3;
    const int col  = nb * 16 + (l & 15);
    const int krow = ks * 32 + (l >> 4) * 8;
    #pragma unroll
    for (int i = 0; i < 8; ++i)
        Wp[(size_t)t * 8 + i] = (unsigned short)bf16_rn(W[(krow + i) * D_OUT + col]);
}

// ---------------------------------------------------------------------------
// PASS 1: coarse binning (R8-proven, 1563 blocks). record: src | dlo<<17.
// ---------------------------------------------------------------------------
__global__ __launch_bounds__(256) void bin_hist_kernel(
        const void* __restrict__ edge_raw, const int* __restrict__ flag,
        int* __restrict__ bucket_alloc, int* __restrict__ binned) {
    __shared__ int cnt[128];
    __shared__ int gbase[128];
    const int tid = threadIdx.x;
    if (tid < 128) cnt[tid] = 0;
    __syncthreads();
    const int is64 = *flag;
    const int base = blockIdx.x * BIN_CHUNK + tid;

#define EDGE_A(i)                                                             \
    int rec##i = 0, pb##i = -1;                                               \
    {                                                                         \
        const int idx = base + (i) * 256;                                     \
        if (idx < N_EDGES) {                                                  \
            const int s = load_src(edge_raw, is64, idx);                      \
            const int d = load_dst(edge_raw, is64, idx);                      \
            if ((unsigned)s < N_NODES && (unsigned)d < N_NODES) {             \
                const int b = d >> 10;                                        \
                const int pos = atomicAdd(&cnt[b], 1);                        \
                rec##i = s | ((d & 1023) << 17);                              \
                pb##i  = pos | (b << 12);                                     \
            }                                                                 \
        }                                                                     \
    }
    EDGE_A(0) EDGE_A(1) EDGE_A(2) EDGE_A(3)
#undef EDGE_A

    __syncthreads();
    if (tid < NBUCK) gbase[tid] = atomicAdd(&bucket_alloc[tid], cnt[tid]);
    __syncthreads();

#define EDGE_B(i)                                                             \
    if (pb##i >= 0) {                                                         \
        const int b = pb##i >> 12;                                            \
        const int p = gbase[b] + (pb##i & 4095);                              \
        if (p < BCAP) binned[b * BCAP + p] = rec##i;                          \
    }
    EDGE_B(0) EDGE_B(1) EDGE_B(2) EDGE_B(3)
#undef EDGE_B
}

// ---------------------------------------------------------------------------
// FUSED pass 2: per-bucket {inline 98-scan of bucket totals -> fine hist ->
// LDS prefix scan -> row_start store -> cursor fill}. Replaces scan98 +
// bucket_fill_scan (R9). One block per bucket, 1024 threads.
// ---------------------------------------------------------------------------
__global__ __launch_bounds__(1024) void bucket_fill_scan_kernel(
        const int* __restrict__ bucket_alloc,
        const int* __restrict__ binned,
        int* __restrict__ row_start, int* __restrict__ csr_pack) {
    __shared__ int hist[1024];
    __shared__ int sb[128];
    const int b   = blockIdx.x;
    const int tid = threadIdx.x;
    hist[tid] = 0;
    if (tid < 128) sb[tid] = (tid < NBUCK) ? bucket_alloc[tid] : 0;
    __syncthreads();

    // inline exclusive scan of the 98 bucket totals (7 steps, trivial)
    for (int off = 1; off < 128; off <<= 1) {
        const int u = (tid >= off && tid < 128) ? sb[tid - off] : 0;
        __syncthreads();
        if (tid < 128) sb[tid] += u;
        __syncthreads();
    }
    int cnt = bucket_alloc[b];
    const int segb = sb[b] - cnt;          // exclusive bucket base in CSR
    if (cnt > BCAP) cnt = BCAP;
    const int base = b * BCAP;

    for (int p = tid; p < cnt; p += 1024)
        atomicAdd(&hist[(binned[base + p] >> 17) & 1023], 1);
    __syncthreads();

    const int myc = hist[tid];
    // inclusive Hillis-Steele scan over 1024 elements
    for (int off = 1; off < 1024; off <<= 1) {
        const int u = (tid >= off) ? hist[tid - off] : 0;
        __syncthreads();
        hist[tid] += u;
        __syncthreads();
    }
    const int rs = segb + hist[tid] - myc;   // exclusive + bucket base
    const int node = (b << 10) + tid;
    if (node <= N_NODES) row_start[node] = rs;   // node==N covers total

    hist[tid] = rs;                         // reuse as cursor
    __syncthreads();

    for (int p = tid; p < cnt; p += 1024) {
        const int rec = binned[base + p];
        const int dlo = (rec >> 17) & 1023;
        const int pos = atomicAdd(&hist[dlo], 1);
        csr_pack[pos] = (rec & 0x1FFFF) | ((dlo & 63) << 20);
    }
}

// ---------------------------------------------------------------------------
// FUSED gather + MFMA GEMM + ReLU. One 64-row tile per 256-thread block.
// Gather phase (wave wv owns rows wv*16..+15): R8's register-run gather, but
// the flush writes packed bf16 straight into the swizzled LDS tile (write
// perm ((lane>>2)^(rr&7))*4|(lane&3) is conflict-free and matches the R6
// MFMA read swizzle). MFMA phase: R6-proven 16x16x32 tile; B-fragments
// loaded per-ks to keep VGPR low during the gather phase.
// Rationale: gather is memory-pipe-bound (42% VALU, 0% MFMA), GEMM is
// MFMA-bound; co-resident blocks in different phases overlap pipes (m114),
// and the 51MB Xg round-trip + one launch disappear.
// ---------------------------------------------------------------------------
__global__ __launch_bounds__(256) void gather_mfma_kernel(
        const float* __restrict__ H,
        const unsigned* __restrict__ Hb,
        const int* __restrict__ row_start,
        const int* __restrict__ csr_pack,
        const unsigned short* __restrict__ Wp,
        float* __restrict__ out) {
    __shared__ unsigned Xs[64 * 64];      // swizzled packed-bf16 tile (16KB)
    __shared__ int idx_lds[4][256];       // 4KB

    const int g    = blockIdx.x * BLK_ROWS;
    const int wv   = threadIdx.x >> 6;
    const int lane = threadIdx.x & 63;
    const int r0   = g + wv * 16;

    if (r0 < N_NODES) {
        int r1 = r0 + 16; if (r1 > N_NODES) r1 = N_NODES;
        const int p0   = row_start[r0];
        const int pend = row_start[r1];

        // degree-0 rows: X = H directly
        for (int r = r0; r < r1; ++r) {
            if (row_start[r + 1] == row_start[r]) {
                const float2 h = ((const float2*)(H + (size_t)r * D_IN))[lane];
                const int rr = r - g;
                Xs[rr * 64 + ((((lane >> 2) ^ (rr & 7)) << 2) | (lane & 3))] =
                    pack2_bf16(h.x, h.y);
            }
        }

        int    cur = -1;
        float2 acc = make_float2(0.f, 0.f);
        float2 hs  = make_float2(0.f, 0.f);

#define FLUSH()                                                               \
        Xs[cur * 64 + ((((lane >> 2) ^ (cur & 7)) << 2) | (lane & 3))] =      \
            pack2_bf16(acc.x + hs.x, acc.y + hs.y);

#define PROC(EV, UU)                                                          \
        {                                                                     \
            const int dl = (EV) >> 20;                                        \
            const float vx = __uint_as_float((UU) << 16);                     \
            const float vy = __uint_as_float((UU) & 0xFFFF0000u);             \
            if (dl != cur) {                                                  \
                if (cur >= 0) { FLUSH(); }                                    \
                cur = dl;                                                     \
                hs  = ((const float2*)(H + (size_t)(g + dl) * D_IN))[lane];   \
                acc = make_float2(vx, vy);                                    \
            } else {                                                          \
                acc.x += vx; acc.y += vy;                                     \
            }                                                                 \
        }

        for (int p = p0; p < pend; p += 256) {
            int m = pend - p;
            if (m > 256) m = 256;
            #pragma unroll
            for (int j = 0; j < 4; ++j) {
                const int o = lane + j * 64;
                if (o < m) idx_lds[wv][o] = csr_pack[p + o];
            }
            int n = 0;
            for (; n + 8 <= m; n += 8) {
                const int e0 = idx_lds[wv][n + 0];
                const int e1 = idx_lds[wv][n + 1];
                const int e2 = idx_lds[wv][n + 2];
                const int e3 = idx_lds[wv][n + 3];
                const int e4 = idx_lds[wv][n + 4];
                const int e5 = idx_lds[wv][n + 5];
                const int e6 = idx_lds[wv][n + 6];
                const int e7 = idx_lds[wv][n + 7];
                const unsigned u0 = Hb[(size_t)(e0 & 0xFFFFF) * 64 + lane];
                const unsigned u1 = Hb[(size_t)(e1 & 0xFFFFF) * 64 + lane];
                const unsigned u2 = Hb[(size_t)(e2 & 0xFFFFF) * 64 + lane];
                const unsigned u3 = Hb[(size_t)(e3 & 0xFFFFF) * 64 + lane];
                const unsigned u4 = Hb[(size_t)(e4 & 0xFFFFF) * 64 + lane];
                const unsigned u5 = Hb[(size_t)(e5 & 0xFFFFF) * 64 + lane];
                const unsigned u6 = Hb[(size_t)(e6 & 0xFFFFF) * 64 + lane];
                const unsigned u7 = Hb[(size_t)(e7 & 0xFFFFF) * 64 + lane];
                PROC(e0, u0) PROC(e1, u1) PROC(e2, u2) PROC(e3, u3)
                PROC(e4, u4) PROC(e5, u5) PROC(e6, u6) PROC(e7, u7)
            }
            for (; n < m; ++n) {
                const int e0 = idx_lds[wv][n];
                const unsigned u = Hb[(size_t)(e0 & 0xFFFFF) * 64 + lane];
                PROC(e0, u)
            }
        }
        if (cur >= 0) { FLUSH(); }
#undef PROC
#undef FLUSH
    }
    __syncthreads();

    // ---- MFMA phase (R6-proven). Rows >= N hold garbage in Xs; their C
    // rows are row-local and the store is guarded. ----
    f32x4 acc4[4][4] = {};
    const int arow = lane & 15;
    const int agrp = lane >> 4;

    #pragma unroll
    for (int ks = 0; ks < 4; ++ks) {
        short8v a0, a1, a2, a3;
        {
            const int r = 0 * 16 + arow;
            a0 = *(const short8v*)(&Xs[r * 64 + ((ks * 4 + agrp) ^ (r & 7)) * 4]);
        }
        {
            const int r = 1 * 16 + arow;
            a1 = *(const short8v*)(&Xs[r * 64 + ((ks * 4 + agrp) ^ (r & 7)) * 4]);
        }
        {
            const int r = 2 * 16 + arow;
            a2 = *(const short8v*)(&Xs[r * 64 + ((ks * 4 + agrp) ^ (r & 7)) * 4]);
        }
        {
            const int r = 3 * 16 + arow;
            a3 = *(const short8v*)(&Xs[r * 64 + ((ks * 4 + agrp) ^ (r & 7)) * 4]);
        }
        #pragma unroll
        for (int nb = 0; nb < 4; ++nb) {
            const int f = (wv * 4 + nb) * 4 + ks;
            const short8v bf = *(const short8v*)(Wp + ((size_t)f * 64 + lane) * 8);
            acc4[0][nb] = __builtin_amdgcn_mfma_f32_16x16x32_bf16(a0, bf, acc4[0][nb], 0, 0, 0);
            acc4[1][nb] = __builtin_amdgcn_mfma_f32_16x16x32_bf16(a1, bf, acc4[1][nb], 0, 0, 0);
            acc4[2][nb] = __builtin_amdgcn_mfma_f32_16x16x32_bf16(a2, bf, acc4[2][nb], 0, 0, 0);
            acc4[3][nb] = __builtin_amdgcn_mfma_f32_16x16x32_bf16(a3, bf, acc4[3][nb], 0, 0, 0);
        }
    }

    #pragma unroll
    for (int mg = 0; mg < 4; ++mg) {
        #pragma unroll
        for (int rr = 0; rr < 4; ++rr) {
            const int row = g + mg * 16 + agrp * 4 + rr;
            if (row < N_NODES) {
                #pragma unroll
                for (int nb = 0; nb < 4; ++nb) {
                    const float v = acc4[mg][nb][rr];
                    out[(size_t)row * D_OUT + wv * 64 + nb * 16 + (lane & 15)] =
                        fmaxf(v, 0.f);
                }
            }
        }
    }
}

// ---------------------------------------------------------------------------
// Fallback-tier CSR build (R4-proven): hist -> scans -> fill
// ---------------------------------------------------------------------------
__global__ __launch_bounds__(256) void hist_kernel(
        const void* __restrict__ edge_raw, const int* __restrict__ flag,
        int* __restrict__ counts) {
    int e = blockIdx.x * blockDim.x + threadIdx.x;
    if (e >= N_EDGES) return;
    int dst = load_dst(edge_raw, *flag, e);
    if ((unsigned)dst < N_NODES) atomicAdd(&counts[dst], 1);
}

__global__ __launch_bounds__(256) void block_sum_kernel(
        const int* __restrict__ counts, int* __restrict__ bsum) {
    __shared__ int lds[256];
    int t = threadIdx.x;
    int i = blockIdx.x * 256 + t;
    lds[t] = (i < N_NODES) ? counts[i] : 0;
    __syncthreads();
    for (int off = 128; off > 0; off >>= 1) {
        if (t < off) lds[t] += lds[t + off];
        __syncthreads();
    }
    if (t == 0) bsum[blockIdx.x] = lds[0];
}

__global__ __launch_bounds__(512) void scan_bsum_kernel(
        int* __restrict__ bsum, int* __restrict__ row_start) {
    __shared__ int lds[512];
    int t = threadIdx.x;
    lds[t] = (t < NB_SCAN) ? bsum[t] : 0;
    __syncthreads();
    for (int off = 1; off < 512; off <<= 1) {
        int u = (t >= off) ? lds[t - off] : 0;
        __syncthreads();
        lds[t] += u;
        __syncthreads();
    }
    int excl = (t == 0) ? 0 : lds[t - 1];
    if (t < NB_SCAN) bsum[t] = excl;
    if (t == 0) row_start[N_NODES] = N_EDGES;
}

__global__ __launch_bounds__(256) void scan_counts_kernel(
        int* __restrict__ counts_cursor, const int* __restrict__ bsum,
        int* __restrict__ row_start) {
    __shared__ int lds[256];
    int t = threadIdx.x;
    int i = blockIdx.x * 256 + t;
    int c = (i < N_NODES) ? counts_cursor[i] : 0;
    lds[t] = c;
    __syncthreads();
    for (int off = 1; off < 256; off <<= 1) {
        int u = (t >= off) ? lds[t - off] : 0;
        __syncthreads();
        lds[t] += u;
        __syncthreads();
    }
    int rs = bsum[blockIdx.x] + lds[t] - c;
    if (i < N_NODES) {
        row_start[i] = rs;
        counts_cursor[i] = rs;
    }
}

__global__ __launch_bounds__(256) void fill_kernel(
        const void* __restrict__ edge_raw, const int* __restrict__ flag,
        int* __restrict__ cursor, int* __restrict__ csr_pack) {
    int e = blockIdx.x * blockDim.x + threadIdx.x;
    if (e >= N_EDGES) return;
    int is64 = *flag;
    int src = load_src(edge_raw, is64, e);
    int dst = load_dst(edge_raw, is64, e);
    if ((unsigned)dst >= N_NODES || (unsigned)src >= N_NODES) return;
    int pos = atomicAdd(&cursor[dst], 1);
    csr_pack[pos] = src | ((dst & 63) << 20);
}

// ---------------------------------------------------------------------------
// Fallback fused FMA kernel (R4-proven) for small ws_size.
// ---------------------------------------------------------------------------
__global__ __launch_bounds__(256) void fused_gather_gemm_relu_kernel(
        const float* __restrict__ H,
        const int* __restrict__ row_start,
        const int* __restrict__ csr_pack,
        const float* __restrict__ Wm,
        float* __restrict__ out) {
    __shared__ float Xs[BLK_ROWS][D_IN];
    __shared__ int idx_lds[4][64];

    const int g    = blockIdx.x * BLK_ROWS;
    const int tid  = threadIdx.x;
    const int wv   = tid >> 6;
    const int lane = tid & 63;

    {
        const int kidx = tid & 31;
        const int rg   = tid >> 5;
        #pragma unroll
        for (int j = 0; j < 8; ++j) {
            const int r = rg + j * 8;
            const int row = g + r;
            float4 x = make_float4(0.f, 0.f, 0.f, 0.f);
            if (row < N_NODES)
                x = *reinterpret_cast<const float4*>(H + (size_t)row * D_IN + kidx * 4);
            *reinterpret_cast<float4*>(&Xs[r][kidx * 4]) = x;
        }
    }
    __syncthreads();

    {
        const int seg_beg = row_start[g];
        const int rend    = (g + BLK_ROWS < N_NODES) ? (g + BLK_ROWS) : N_NODES;
        const int seg_end = row_start[rend];
        const int len     = seg_end - seg_beg;
        const int clen    = (len + 3) >> 2;
        const int cbeg    = seg_beg + wv * clen;
        int cend          = cbeg + clen;
        if (cend > seg_end) cend = seg_end;

        const int c2 = lane * 2;
        int   cur = -1;
        float2 acc = make_float2(0.f, 0.f);

#define PROCF(EV, VV)                                                         \
        {                                                                     \
            const int dl = (EV) >> 20;                                        \
            if (dl != cur) {                                                  \
                if (cur >= 0) {                                               \
                    atomicAdd(&Xs[cur][c2],     acc.x);                       \
                    atomicAdd(&Xs[cur][c2 + 1], acc.y);                       \
                }                                                             \
                cur = dl;                                                     \
                acc = (VV);                                                   \
            } else {                                                          \
                acc.x += (VV).x; acc.y += (VV).y;                             \
            }                                                                 \
        }

        for (int base = cbeg; base < cend; base += 64) {
            int m = cend - base;
            if (m > 64) m = 64;
            if (lane < m) idx_lds[wv][lane] = csr_pack[base + lane];
            int n = 0;
            for (; n + 8 <= m; n += 8) {
                const int e0 = idx_lds[wv][n + 0];
                const int e1 = idx_lds[wv][n + 1];
                const int e2 = idx_lds[wv][n + 2];
                const int e3 = idx_lds[wv][n + 3];
                const int e4 = idx_lds[wv][n + 4];
                const int e5 = idx_lds[wv][n + 5];
                const int e6 = idx_lds[wv][n + 6];
                const int e7 = idx_lds[wv][n + 7];
                const float2 v0 = ((const float2*)(H + (size_t)(e0 & 0xFFFFF) * D_IN))[lane];
                const float2 v1 = ((const float2*)(H + (size_t)(e1 & 0xFFFFF) * D_IN))[lane];
                const float2 v2 = ((const float2*)(H + (size_t)(e2 & 0xFFFFF) * D_IN))[lane];
                const float2 v3 = ((const float2*)(H + (size_t)(e3 & 0xFFFFF) * D_IN))[lane];
                const float2 v4 = ((const float2*)(H + (size_t)(e4 & 0xFFFFF) * D_IN))[lane];
                const float2 v5 = ((const float2*)(H + (size_t)(e5 & 0xFFFFF) * D_IN))[lane];
                const float2 v6 = ((const float2*)(H + (size_t)(e6 & 0xFFFFF) * D_IN))[lane];
                const float2 v7 = ((const float2*)(H + (size_t)(e7 & 0xFFFFF) * D_IN))[lane];
                PROCF(e0, v0) PROCF(e1, v1) PROCF(e2, v2) PROCF(e3, v3)
                PROCF(e4, v4) PROCF(e5, v5) PROCF(e6, v6) PROCF(e7, v7)
            }
            for (; n < m; ++n) {
                const int e0 = idx_lds[wv][n];
                const float2 v = ((const float2*)(H + (size_t)(e0 & 0xFFFFF) * D_IN))[lane];
                PROCF(e0, v)
            }
        }
        if (cur >= 0) {
            atomicAdd(&Xs[cur][c2],     acc.x);
            atomicAdd(&Xs[cur][c2 + 1], acc.y);
        }
#undef PROCF
    }
    __syncthreads();

    const int ty = tid >> 6;
    const int tx = tid & 63;

    float accv[16][4];
    #pragma unroll
    for (int r = 0; r < 16; ++r)
        #pragma unroll
        for (int j = 0; j < 4; ++j) accv[r][j] = 0.f;

    const float* Wp2 = Wm + tx * 4;

    #pragma unroll 2
    for (int k = 0; k < D_IN; k += 4) {
        const float4 w0 = *reinterpret_cast<const float4*>(Wp2 + (k + 0) * D_OUT);
        const float4 w1 = *reinterpret_cast<const float4*>(Wp2 + (k + 1) * D_OUT);
        const float4 w2 = *reinterpret_cast<const float4*>(Wp2 + (k + 2) * D_OUT);
        const float4 w3 = *reinterpret_cast<const float4*>(Wp2 + (k + 3) * D_OUT);
        #pragma unroll
        for (int r = 0; r < 16; ++r) {
            const float4 x = *reinterpret_cast<const float4*>(&Xs[ty * 16 + r][k]);
            accv[r][0] = fmaf(x.x, w0.x, accv[r][0]);
            accv[r][0] = fmaf(x.y, w1.x, accv[r][0]);
            accv[r][0] = fmaf(x.z, w2.x, accv[r][0]);
            accv[r][0] = fmaf(x.w, w3.x, accv[r][0]);
            accv[r][1] = fmaf(x.x, w0.y, accv[r][1]);
            accv[r][1] = fmaf(x.y, w1.y, accv[r][1]);
            accv[r][1] = fmaf(x.z, w2.y, accv[r][1]);
            accv[r][1] = fmaf(x.w, w3.y, accv[r][1]);
            accv[r][2] = fmaf(x.x, w0.z, accv[r][2]);
            accv[r][2] = fmaf(x.y, w1.z, accv[r][2]);
            accv[r][2] = fmaf(x.z, w2.z, accv[r][2]);
            accv[r][2] = fmaf(x.w, w3.z, accv[r][2]);
            accv[r][3] = fmaf(x.x, w0.w, accv[r][3]);
            accv[r][3] = fmaf(x.y, w1.w, accv[r][3]);
            accv[r][3] = fmaf(x.z, w2.w, accv[r][3]);
            accv[r][3] = fmaf(x.w, w3.w, accv[r][3]);
        }
    }

    #pragma unroll
    for (int r = 0; r < 16; ++r) {
        const int row = g + ty * 16 + r;
        if (row < N_NODES) {
            float4 o;
            o.x = fmaxf(accv[r][0], 0.f);
            o.y = fmaxf(accv[r][1], 0.f);
            o.z = fmaxf(accv[r][2], 0.f);
            o.w = fmaxf(accv[r][3], 0.f);
            *reinterpret_cast<float4*>(out + (size_t)row * D_OUT + tx * 4) = o;
        }
    }
}

extern "C" void kernel_launch(void* const* d_in, const int* in_sizes, int n_in,
                              void* d_out, int out_size, void* d_ws, size_t ws_size,
                              hipStream_t stream) {
    const float* H    = (const float*)d_in[0];
    const void*  edge = d_in[1];
    const float* Wm   = (const float*)d_in[2];
    float* out = (float*)d_out;

    // workspace layout (identical to R9; main path uses a subset)
    const size_t off_rs    = 0;
    const size_t off_cur   = ((size_t)(N_NODES + 1) * 4 + 15) & ~(size_t)15;
    const size_t off_alloc = off_cur + (size_t)N_NODES * 4;          // 128 ints
    const size_t off_csr   = off_alloc + 512;
    const size_t off_bsum  = off_csr + (size_t)N_EDGES * 4;
    const size_t off_flag  = off_bsum + (((size_t)NB_SCAN * 4 + 15) & ~(size_t)15);
    const size_t off_wp    = (off_flag + 16 + 255) & ~(size_t)255;
    const size_t off_X     = (off_wp + 64 * 64 * 16 + 255) & ~(size_t)255;
    const size_t need_mid  = off_X + (size_t)X_ROWS * 64 * sizeof(unsigned);
    const size_t off_Hb    = (need_mid + 255) & ~(size_t)255;
    const size_t need_full = off_Hb + (size_t)N_NODES * (D_IN / 2) * sizeof(unsigned);
    const size_t off_bin   = (need_full + 255) & ~(size_t)255;
    const size_t need_sort = off_bin + (size_t)NBUCK * BCAP * 4;

    int* row_start = (int*)((char*)d_ws + off_rs);
    int* cursor    = (int*)((char*)d_ws + off_cur);   // fallback tier only
    int* balloc    = (int*)((char*)d_ws + off_alloc);
    int* csr_pack  = (int*)((char*)d_ws + off_csr);
    int* bsum      = (int*)((char*)d_ws + off_bsum);  // fallback tier only
    int* flag      = (int*)((char*)d_ws + off_flag);
    unsigned short* Wp = (unsigned short*)((char*)d_ws + off_wp);
    unsigned* Hb   = (unsigned*)((char*)d_ws + off_Hb);
    int* binned    = (int*)((char*)d_ws + off_bin);

    detect_idx64_kernel<<<1, 128, 0, stream>>>((const int*)edge, flag, balloc);

    const int edge_blocks = (N_EDGES + 255) / 256;

    if (ws_size >= need_sort) {
        // main path: 6 dispatches total
        pack_w_kernel<<<16, 256, 0, stream>>>(Wm, Wp);
        cvt_h_kernel<<<(N_NODES * (D_IN / 2) + 255) / 256, 256, 0, stream>>>(H, Hb);
        bin_hist_kernel<<<BIN_BLOCKS, 256, 0, stream>>>(edge, flag, balloc, binned);
        bucket_fill_scan_kernel<<<NBUCK, 1024, 0, stream>>>(
            balloc, binned, row_start, csr_pack);
        gather_mfma_kernel<<<N_TILES, 256, 0, stream>>>(
            H, Hb, row_start, csr_pack, Wp, out);
    } else {
        hipMemsetAsync(cursor, 0, (size_t)N_NODES * 4 + 512, stream);
        hist_kernel<<<edge_blocks, 256, 0, stream>>>(edge, flag, cursor);
        block_sum_kernel<<<NB_SCAN, 256, 0, stream>>>(cursor, bsum);
        scan_bsum_kernel<<<1, 512, 0, stream>>>(bsum, row_start);
        scan_counts_kernel<<<NB_SCAN, 256, 0, stream>>>(cursor, bsum, row_start);
        fill_kernel<<<edge_blocks, 256, 0, stream>>>(edge, flag, cursor, csr_pack);
        fused_gather_gemm_relu_kernel<<<N_TILES, 256, 0, stream>>>(
            H, row_start, csr_pack, Wm, out);
    }
}

// Round 12
// 179.391 us; speedup vs baseline: 1.1502x; 1.1502x over previous
//
#include <hip/hip_runtime.h>

#define N_NODES 100000
#define N_EDGES 1600000
#define D_IN    128
#define D_OUT   256
#define NB_SCAN ((N_NODES + 255) / 256)
#define BLK_ROWS 64
#define N_TILES  ((N_NODES + BLK_ROWS - 1) / BLK_ROWS)   // 1563
#define X_ROWS   (N_TILES * BLK_ROWS)                    // 100032 (padded)

#define NBUCK      98
#define BCAP       20480
#define BIN_CHUNK  1024
#define BIN_BLOCKS ((N_EDGES + BIN_CHUNK - 1) / BIN_CHUNK)   // 1563
#define CVT_BLOCKS ((N_NODES * (D_IN / 2) + 255) / 256)      // 25000
#define PACK_BLOCKS 16

#define GBLK_ROWS  32
#define G_TILES    ((N_NODES + GBLK_ROWS - 1) / GBLK_ROWS)   // 3125

typedef __attribute__((ext_vector_type(8))) short short8v;
typedef __attribute__((ext_vector_type(4))) float f32x4;

__device__ __forceinline__ unsigned bf16_rn(float f) {
    unsigned u = __float_as_uint(f);
    return (u + 0x7FFFu + ((u >> 16) & 1u)) >> 16;
}
__device__ __forceinline__ unsigned pack2_bf16(float a, float b) {
    return bf16_rn(a) | (bf16_rn(b) << 16);
}

// ---------------------------------------------------------------------------
// Detect int64 vs int32 edge_index; zeroes bucket_alloc.
// ---------------------------------------------------------------------------
__global__ void detect_idx64_kernel(const int* __restrict__ edge32,
                                    int* __restrict__ flag,
                                    int* __restrict__ balloc) {
    const int t = threadIdx.x;
    if (t < 128) balloc[t] = 0;
    if (t == 0 && blockIdx.x == 0) {
        int is64 = 1;
        for (int i = 1; i < 32; i += 2) {
            if (edge32[i] != 0) { is64 = 0; break; }
        }
        *flag = is64;
    }
}

__device__ __forceinline__ int load_dst(const void* edge_raw, int is64, int e) {
    if (is64) return (int)((const long long*)edge_raw)[(long long)N_EDGES + e];
    return ((const int*)edge_raw)[N_EDGES + e];
}
__device__ __forceinline__ int load_src(const void* edge_raw, int is64, int e) {
    if (is64) return (int)((const long long*)edge_raw)[e];
    return ((const int*)edge_raw)[e];
}

// ---------------------------------------------------------------------------
// PREP: one grid, three independent jobs (block-range partition):
//   [0,16)            pack W -> bf16 MFMA B-fragments (R6 layout)
//   [16,16+25000)     cvt H -> packed bf16
//   [16+25000, +1563) coarse binning (R8-proven)
// Saves 2 launch gaps; bin's LDS-atomic latency overlaps cvt's streaming.
// ---------------------------------------------------------------------------
__global__ __launch_bounds__(256) void prep_kernel(
        const float* __restrict__ W, unsigned short* __restrict__ Wp,
        const float* __restrict__ H, unsigned* __restrict__ Hb,
        const void* __restrict__ edge_raw, const int* __restrict__ flag,
        int* __restrict__ bucket_alloc, int* __restrict__ binned) {
    const int blk = blockIdx.x;
    const int tid = threadIdx.x;

    if (blk < PACK_BLOCKS) {
        // ---- pack W ----
        const int t = blk * 256 + tid;        // 0..4095
        const int f  = t >> 6;
        const int l  = t & 63;
        const int nb = f >> 2;
        const int ks = f & 3;
        const int col  = nb * 16 + (l & 15);
        const int krow = ks * 32 + (l >> 4) * 8;
        #pragma unroll
        for (int i = 0; i < 8; ++i)
            Wp[(size_t)t * 8 + i] =
                (unsigned short)bf16_rn(W[(krow + i) * D_OUT + col]);
        return;
    }
    if (blk < PACK_BLOCKS + CVT_BLOCKS) {
        // ---- cvt H ----
        const int i = (blk - PACK_BLOCKS) * 256 + tid;
        if (i < N_NODES * (D_IN / 2)) {
            const float2 h = ((const float2*)H)[i];
            Hb[i] = pack2_bf16(h.x, h.y);
        }
        return;
    }

    // ---- coarse binning ----
    __shared__ int cnt[128];
    __shared__ int gbase[128];
    if (tid < 128) cnt[tid] = 0;
    __syncthreads();
    const int is64 = *flag;
    const int base = (blk - PACK_BLOCKS - CVT_BLOCKS) * BIN_CHUNK + tid;

#define EDGE_A(i)                                                             \
    int rec##i = 0, pb##i = -1;                                               \
    {                                                                         \
        const int idx = base + (i) * 256;                                     \
        if (idx < N_EDGES) {                                                  \
            const int s = load_src(edge_raw, is64, idx);                      \
            const int d = load_dst(edge_raw, is64, idx);                      \
            if ((unsigned)s < N_NODES && (unsigned)d < N_NODES) {             \
                const int b = d >> 10;                                        \
                const int pos = atomicAdd(&cnt[b], 1);                        \
                rec##i = s | ((d & 1023) << 17);                              \
                pb##i  = pos | (b << 12);                                     \
            }                                                                 \
        }                                                                     \
    }
    EDGE_A(0) EDGE_A(1) EDGE_A(2) EDGE_A(3)
#undef EDGE_A

    __syncthreads();
    if (tid < NBUCK) gbase[tid] = atomicAdd(&bucket_alloc[tid], cnt[tid]);
    __syncthreads();

#define EDGE_B(i)                                                             \
    if (pb##i >= 0) {                                                         \
        const int b = pb##i >> 12;                                            \
        const int p = gbase[b] + (pb##i & 4095);                              \
        if (p < BCAP) binned[b * BCAP + p] = rec##i;                          \
    }
    EDGE_B(0) EDGE_B(1) EDGE_B(2) EDGE_B(3)
#undef EDGE_B
}

// ---------------------------------------------------------------------------
// FUSED pass 2 (R10-proven): per-bucket {inline 98-scan -> fine hist ->
// LDS prefix scan -> row_start -> cursor fill}. L2-merged CSR writes.
// ---------------------------------------------------------------------------
__global__ __launch_bounds__(1024) void bucket_fill_scan_kernel(
        const int* __restrict__ bucket_alloc,
        const int* __restrict__ binned,
        int* __restrict__ row_start, int* __restrict__ csr_pack) {
    __shared__ int hist[1024];
    __shared__ int sb[128];
    const int b   = blockIdx.x;
    const int tid = threadIdx.x;
    hist[tid] = 0;
    if (tid < 128) sb[tid] = (tid < NBUCK) ? bucket_alloc[tid] : 0;
    __syncthreads();

    for (int off = 1; off < 128; off <<= 1) {
        const int u = (tid >= off && tid < 128) ? sb[tid - off] : 0;
        __syncthreads();
        if (tid < 128) sb[tid] += u;
        __syncthreads();
    }
    int cnt = bucket_alloc[b];
    const int segb = sb[b] - cnt;
    if (cnt > BCAP) cnt = BCAP;
    const int base = b * BCAP;

    for (int p = tid; p < cnt; p += 1024)
        atomicAdd(&hist[(binned[base + p] >> 17) & 1023], 1);
    __syncthreads();

    const int myc = hist[tid];
    for (int off = 1; off < 1024; off <<= 1) {
        const int u = (tid >= off) ? hist[tid - off] : 0;
        __syncthreads();
        hist[tid] += u;
        __syncthreads();
    }
    const int rs = segb + hist[tid] - myc;
    const int node = (b << 10) + tid;
    if (node <= N_NODES) row_start[node] = rs;

    hist[tid] = rs;
    __syncthreads();

    for (int p = tid; p < cnt; p += 1024) {
        const int rec = binned[base + p];
        const int dlo = (rec >> 17) & 1023;
        const int pos = atomicAdd(&hist[dlo], 1);
        csr_pack[pos] = (rec & 0x1FFFF) | ((dlo & 63) << 20);
    }
}

// ---------------------------------------------------------------------------
// Gather (R9-proven: 32-row blocks, 8 rows/wave, register-run accumulation,
// nt stores). Traffic-bound at ~72us (nt-store falsifier R9).
// ---------------------------------------------------------------------------
__global__ __launch_bounds__(256) void gather_bf16_kernel(
        const float* __restrict__ H,
        const unsigned* __restrict__ Hb,
        const int* __restrict__ row_start,
        const int* __restrict__ csr_pack,
        unsigned* __restrict__ Xg) {
    __shared__ int idx_lds[4][256];

    const int gb   = blockIdx.x * GBLK_ROWS;
    const int tile = (gb >> 6) << 6;
    const int wv   = threadIdx.x >> 6;
    const int lane = threadIdx.x & 63;
    const int r0   = gb + wv * 8;
    if (r0 >= N_NODES) return;
    int r1 = r0 + 8; if (r1 > N_NODES) r1 = N_NODES;

    const int p0   = row_start[r0];
    const int pend = row_start[r1];

    for (int r = r0; r < r1; ++r) {
        if (row_start[r + 1] == row_start[r]) {
            const float2 h = ((const float2*)(H + (size_t)r * D_IN))[lane];
            __builtin_nontemporal_store(pack2_bf16(h.x, h.y),
                                        &Xg[(size_t)r * 64 + lane]);
        }
    }

    int    cur = -1;
    float2 acc = make_float2(0.f, 0.f);
    float2 hs  = make_float2(0.f, 0.f);

#define FLUSH()                                                               \
    __builtin_nontemporal_store(pack2_bf16(acc.x + hs.x, acc.y + hs.y),       \
                                &Xg[(size_t)(tile + cur) * 64 + lane]);

#define PROC(EV, UU)                                                          \
    {                                                                         \
        const int dl = (EV) >> 20;                                            \
        const float vx = __uint_as_float((UU) << 16);                         \
        const float vy = __uint_as_float((UU) & 0xFFFF0000u);                 \
        if (dl != cur) {                                                      \
            if (cur >= 0) { FLUSH(); }                                        \
            cur = dl;                                                         \
            hs  = ((const float2*)(H + (size_t)(tile + dl) * D_IN))[lane];    \
            acc = make_float2(vx, vy);                                        \
        } else {                                                              \
            acc.x += vx; acc.y += vy;                                         \
        }                                                                     \
    }

    for (int p = p0; p < pend; p += 256) {
        int m = pend - p;
        if (m > 256) m = 256;
        #pragma unroll
        for (int j = 0; j < 4; ++j) {
            const int o = lane + j * 64;
            if (o < m) idx_lds[wv][o] = csr_pack[p + o];
        }
        int n = 0;
        for (; n + 8 <= m; n += 8) {
            const int e0 = idx_lds[wv][n + 0];
            const int e1 = idx_lds[wv][n + 1];
            const int e2 = idx_lds[wv][n + 2];
            const int e3 = idx_lds[wv][n + 3];
            const int e4 = idx_lds[wv][n + 4];
            const int e5 = idx_lds[wv][n + 5];
            const int e6 = idx_lds[wv][n + 6];
            const int e7 = idx_lds[wv][n + 7];
            const unsigned u0 = Hb[(size_t)(e0 & 0xFFFFF) * 64 + lane];
            const unsigned u1 = Hb[(size_t)(e1 & 0xFFFFF) * 64 + lane];
            const unsigned u2 = Hb[(size_t)(e2 & 0xFFFFF) * 64 + lane];
            const unsigned u3 = Hb[(size_t)(e3 & 0xFFFFF) * 64 + lane];
            const unsigned u4 = Hb[(size_t)(e4 & 0xFFFFF) * 64 + lane];
            const unsigned u5 = Hb[(size_t)(e5 & 0xFFFFF) * 64 + lane];
            const unsigned u6 = Hb[(size_t)(e6 & 0xFFFFF) * 64 + lane];
            const unsigned u7 = Hb[(size_t)(e7 & 0xFFFFF) * 64 + lane];
            PROC(e0, u0) PROC(e1, u1) PROC(e2, u2) PROC(e3, u3)
            PROC(e4, u4) PROC(e5, u5) PROC(e6, u6) PROC(e7, u7)
        }
        for (; n < m; ++n) {
            const int e0 = idx_lds[wv][n];
            const unsigned u = Hb[(size_t)(e0 & 0xFFFFF) * 64 + lane];
            PROC(e0, u)
        }
    }
    if (cur >= 0) { FLUSH(); }
#undef PROC
#undef FLUSH
}

// ---------------------------------------------------------------------------
// MFMA GEMM (R6-proven)
// ---------------------------------------------------------------------------
__global__ __launch_bounds__(256) void gemm_mfma_kernel(
        const unsigned* __restrict__ Xg,
        const unsigned short* __restrict__ Wp,
        float* __restrict__ out) {
    __shared__ unsigned Xs[64 * 64];

    const int tid = threadIdx.x;
    const int w   = tid >> 6;
    const int l   = tid & 63;
    const int g   = blockIdx.x * BLK_ROWS;

    #pragma unroll
    for (int j = 0; j < 4; ++j) {
        const int flat = j * 256 + tid;
        const int r   = flat >> 4;
        const int c16 = flat & 15;
        const uint4 v = *(const uint4*)(Xg + (size_t)(g + r) * 64 + c16 * 4);
        const int pc = c16 ^ (r & 7);
        *(uint4*)(&Xs[r * 64 + pc * 4]) = v;
    }

    short8v bfr[4][4];
    #pragma unroll
    for (int nb = 0; nb < 4; ++nb)
        #pragma unroll
        for (int ks = 0; ks < 4; ++ks) {
            const int f = (w * 4 + nb) * 4 + ks;
            bfr[nb][ks] = *(const short8v*)(Wp + ((size_t)f * 64 + l) * 8);
        }

    __syncthreads();

    f32x4 acc[4][4] = {};
    const int arow = l & 15;
    const int agrp = l >> 4;

    #pragma unroll
    for (int ks = 0; ks < 4; ++ks) {
        short8v a0, a1, a2, a3;
        {
            const int r = 0 * 16 + arow;
            a0 = *(const short8v*)(&Xs[r * 64 + ((ks * 4 + agrp) ^ (r & 7)) * 4]);
        }
        {
            const int r = 1 * 16 + arow;
            a1 = *(const short8v*)(&Xs[r * 64 + ((ks * 4 + agrp) ^ (r & 7)) * 4]);
        }
        {
            const int r = 2 * 16 + arow;
            a2 = *(const short8v*)(&Xs[r * 64 + ((ks * 4 + agrp) ^ (r & 7)) * 4]);
        }
        {
            const int r = 3 * 16 + arow;
            a3 = *(const short8v*)(&Xs[r * 64 + ((ks * 4 + agrp) ^ (r & 7)) * 4]);
        }
        #pragma unroll
        for (int nb = 0; nb < 4; ++nb) {
            acc[0][nb] = __builtin_amdgcn_mfma_f32_16x16x32_bf16(a0, bfr[nb][ks], acc[0][nb], 0, 0, 0);
            acc[1][nb] = __builtin_amdgcn_mfma_f32_16x16x32_bf16(a1, bfr[nb][ks], acc[1][nb], 0, 0, 0);
            acc[2][nb] = __builtin_amdgcn_mfma_f32_16x16x32_bf16(a2, bfr[nb][ks], acc[2][nb], 0, 0, 0);
            acc[3][nb] = __builtin_amdgcn_mfma_f32_16x16x32_bf16(a3, bfr[nb][ks], acc[3][nb], 0, 0, 0);
        }
    }

    #pragma unroll
    for (int mg = 0; mg < 4; ++mg) {
        #pragma unroll
        for (int rr = 0; rr < 4; ++rr) {
            const int row = g + mg * 16 + agrp * 4 + rr;
            if (row < N_NODES) {
                #pragma unroll
                for (int nb = 0; nb < 4; ++nb) {
                    const float v = acc[mg][nb][rr];
                    out[(size_t)row * D_OUT + w * 64 + nb * 16 + (l & 15)] =
                        fmaxf(v, 0.f);
                }
            }
        }
    }
}

// ---------------------------------------------------------------------------
// Fallback-tier CSR build (R4-proven): hist -> scans -> fill
// ---------------------------------------------------------------------------
__global__ __launch_bounds__(256) void hist_kernel(
        const void* __restrict__ edge_raw, const int* __restrict__ flag,
        int* __restrict__ counts) {
    int e = blockIdx.x * blockDim.x + threadIdx.x;
    if (e >= N_EDGES) return;
    int dst = load_dst(edge_raw, *flag, e);
    if ((unsigned)dst < N_NODES) atomicAdd(&counts[dst], 1);
}

__global__ __launch_bounds__(256) void block_sum_kernel(
        const int* __restrict__ counts, int* __restrict__ bsum) {
    __shared__ int lds[256];
    int t = threadIdx.x;
    int i = blockIdx.x * 256 + t;
    lds[t] = (i < N_NODES) ? counts[i] : 0;
    __syncthreads();
    for (int off = 128; off > 0; off >>= 1) {
        if (t < off) lds[t] += lds[t + off];
        __syncthreads();
    }
    if (t == 0) bsum[blockIdx.x] = lds[0];
}

__global__ __launch_bounds__(512) void scan_bsum_kernel(
        int* __restrict__ bsum, int* __restrict__ row_start) {
    __shared__ int lds[512];
    int t = threadIdx.x;
    lds[t] = (t < NB_SCAN) ? bsum[t] : 0;
    __syncthreads();
    for (int off = 1; off < 512; off <<= 1) {
        int u = (t >= off) ? lds[t - off] : 0;
        __syncthreads();
        lds[t] += u;
        __syncthreads();
    }
    int excl = (t == 0) ? 0 : lds[t - 1];
    if (t < NB_SCAN) bsum[t] = excl;
    if (t == 0) row_start[N_NODES] = N_EDGES;
}

__global__ __launch_bounds__(256) void scan_counts_kernel(
        int* __restrict__ counts_cursor, const int* __restrict__ bsum,
        int* __restrict__ row_start) {
    __shared__ int lds[256];
    int t = threadIdx.x;
    int i = blockIdx.x * 256 + t;
    int c = (i < N_NODES) ? counts_cursor[i] : 0;
    lds[t] = c;
    __syncthreads();
    for (int off = 1; off < 256; off <<= 1) {
        int u = (t >= off) ? lds[t - off] : 0;
        __syncthreads();
        lds[t] += u;
        __syncthreads();
    }
    int rs = bsum[blockIdx.x] + lds[t] - c;
    if (i < N_NODES) {
        row_start[i] = rs;
        counts_cursor[i] = rs;
    }
}

__global__ __launch_bounds__(256) void fill_kernel(
        const void* __restrict__ edge_raw, const int* __restrict__ flag,
        int* __restrict__ cursor, int* __restrict__ csr_pack) {
    int e = blockIdx.x * blockDim.x + threadIdx.x;
    if (e >= N_EDGES) return;
    int is64 = *flag;
    int src = load_src(edge_raw, is64, e);
    int dst = load_dst(edge_raw, is64, e);
    if ((unsigned)dst >= N_NODES || (unsigned)src >= N_NODES) return;
    int pos = atomicAdd(&cursor[dst], 1);
    csr_pack[pos] = src | ((dst & 63) << 20);
}

// ---------------------------------------------------------------------------
// Fallback fused FMA kernel (R4-proven) for small ws_size.
// ---------------------------------------------------------------------------
__global__ __launch_bounds__(256) void fused_gather_gemm_relu_kernel(
        const float* __restrict__ H,
        const int* __restrict__ row_start,
        const int* __restrict__ csr_pack,
        const float* __restrict__ Wm,
        float* __restrict__ out) {
    __shared__ float Xs[BLK_ROWS][D_IN];
    __shared__ int idx_lds[4][64];

    const int g    = blockIdx.x * BLK_ROWS;
    const int tid  = threadIdx.x;
    const int wv   = tid >> 6;
    const int lane = tid & 63;

    {
        const int kidx = tid & 31;
        const int rg   = tid >> 5;
        #pragma unroll
        for (int j = 0; j < 8; ++j) {
            const int r = rg + j * 8;
            const int row = g + r;
            float4 x = make_float4(0.f, 0.f, 0.f, 0.f);
            if (row < N_NODES)
                x = *reinterpret_cast<const float4*>(H + (size_t)row * D_IN + kidx * 4);
            *reinterpret_cast<float4*>(&Xs[r][kidx * 4]) = x;
        }
    }
    __syncthreads();

    {
        const int seg_beg = row_start[g];
        const int rend    = (g + BLK_ROWS < N_NODES) ? (g + BLK_ROWS) : N_NODES;
        const int seg_end = row_start[rend];
        const int len     = seg_end - seg_beg;
        const int clen    = (len + 3) >> 2;
        const int cbeg    = seg_beg + wv * clen;
        int cend          = cbeg + clen;
        if (cend > seg_end) cend = seg_end;

        const int c2 = lane * 2;
        int   cur = -1;
        float2 acc = make_float2(0.f, 0.f);

#define PROCF(EV, VV)                                                         \
        {                                                                     \
            const int dl = (EV) >> 20;                                        \
            if (dl != cur) {                                                  \
                if (cur >= 0) {                                               \
                    atomicAdd(&Xs[cur][c2],     acc.x);                       \
                    atomicAdd(&Xs[cur][c2 + 1], acc.y);                       \
                }                                                             \
                cur = dl;                                                     \
                acc = (VV);                                                   \
            } else {                                                          \
                acc.x += (VV).x; acc.y += (VV).y;                             \
            }                                                                 \
        }

        for (int base = cbeg; base < cend; base += 64) {
            int m = cend - base;
            if (m > 64) m = 64;
            if (lane < m) idx_lds[wv][lane] = csr_pack[base + lane];
            int n = 0;
            for (; n + 8 <= m; n += 8) {
                const int e0 = idx_lds[wv][n + 0];
                const int e1 = idx_lds[wv][n + 1];
                const int e2 = idx_lds[wv][n + 2];
                const int e3 = idx_lds[wv][n + 3];
                const int e4 = idx_lds[wv][n + 4];
                const int e5 = idx_lds[wv][n + 5];
                const int e6 = idx_lds[wv][n + 6];
                const int e7 = idx_lds[wv][n + 7];
                const float2 v0 = ((const float2*)(H + (size_t)(e0 & 0xFFFFF) * D_IN))[lane];
                const float2 v1 = ((const float2*)(H + (size_t)(e1 & 0xFFFFF) * D_IN))[lane];
                const float2 v2 = ((const float2*)(H + (size_t)(e2 & 0xFFFFF) * D_IN))[lane];
                const float2 v3 = ((const float2*)(H + (size_t)(e3 & 0xFFFFF) * D_IN))[lane];
                const float2 v4 = ((const float2*)(H + (size_t)(e4 & 0xFFFFF) * D_IN))[lane];
                const float2 v5 = ((const float2*)(H + (size_t)(e5 & 0xFFFFF) * D_IN))[lane];
                const float2 v6 = ((const float2*)(H + (size_t)(e6 & 0xFFFFF) * D_IN))[lane];
                const float2 v7 = ((const float2*)(H + (size_t)(e7 & 0xFFFFF) * D_IN))[lane];
                PROCF(e0, v0) PROCF(e1, v1) PROCF(e2, v2) PROCF(e3, v3)
                PROCF(e4, v4) PROCF(e5, v5) PROCF(e6, v6) PROCF(e7, v7)
            }
            for (; n < m; ++n) {
                const int e0 = idx_lds[wv][n];
                const float2 v = ((const float2*)(H + (size_t)(e0 & 0xFFFFF) * D_IN))[lane];
                PROCF(e0, v)
            }
        }
        if (cur >= 0) {
            atomicAdd(&Xs[cur][c2],     acc.x);
            atomicAdd(&Xs[cur][c2 + 1], acc.y);
        }
#undef PROCF
    }
    __syncthreads();

    const int ty = tid >> 6;
    const int tx = tid & 63;

    float accv[16][4];
    #pragma unroll
    for (int r = 0; r < 16; ++r)
        #pragma unroll
        for (int j = 0; j < 4; ++j) accv[r][j] = 0.f;

    const float* Wp2 = Wm + tx * 4;

    #pragma unroll 2
    for (int k = 0; k < D_IN; k += 4) {
        const float4 w0 = *reinterpret_cast<const float4*>(Wp2 + (k + 0) * D_OUT);
        const float4 w1 = *reinterpret_cast<const float4*>(Wp2 + (k + 1) * D_OUT);
        const float4 w2 = *reinterpret_cast<const float4*>(Wp2 + (k + 2) * D_OUT);
        const float4 w3 = *reinterpret_cast<const float4*>(Wp2 + (k + 3) * D_OUT);
        #pragma unroll
        for (int r = 0; r < 16; ++r) {
            const float4 x = *reinterpret_cast<const float4*>(&Xs[ty * 16 + r][k]);
            accv[r][0] = fmaf(x.x, w0.x, accv[r][0]);
            accv[r][0] = fmaf(x.y, w1.x, accv[r][0]);
            accv[r][0] = fmaf(x.z, w2.x, accv[r][0]);
            accv[r][0] = fmaf(x.w, w3.x, accv[r][0]);
            accv[r][1] = fmaf(x.x, w0.y, accv[r][1]);
            accv[r][1] = fmaf(x.y, w1.y, accv[r][1]);
            accv[r][1] = fmaf(x.z, w2.y, accv[r][1]);
            accv[r][1] = fmaf(x.w, w3.y, accv[r][1]);
            accv[r][2] = fmaf(x.x, w0.z, accv[r][2]);
            accv[r][2] = fmaf(x.y, w1.z, accv[r][2]);
            accv[r][2] = fmaf(x.z, w2.z, accv[r][2]);
            accv[r][2] = fmaf(x.w, w3.z, accv[r][2]);
            accv[r][3] = fmaf(x.x, w0.w, accv[r][3]);
            accv[r][3] = fmaf(x.y, w1.w, accv[r][3]);
            accv[r][3] = fmaf(x.z, w2.w, accv[r][3]);
            accv[r][3] = fmaf(x.w, w3.w, accv[r][3]);
        }
    }

    #pragma unroll
    for (int r = 0; r < 16; ++r) {
        const int row = g + ty * 16 + r;
        if (row < N_NODES) {
            float4 o;
            o.x = fmaxf(accv[r][0], 0.f);
            o.y = fmaxf(accv[r][1], 0.f);
            o.z = fmaxf(accv[r][2], 0.f);
            o.w = fmaxf(accv[r][3], 0.f);
            *reinterpret_cast<float4*>(out + (size_t)row * D_OUT + tx * 4) = o;
        }
    }
}

extern "C" void kernel_launch(void* const* d_in, const int* in_sizes, int n_in,
                              void* d_out, int out_size, void* d_ws, size_t ws_size,
                              hipStream_t stream) {
    const float* H    = (const float*)d_in[0];
    const void*  edge = d_in[1];
    const float* Wm   = (const float*)d_in[2];
    float* out = (float*)d_out;

    const size_t off_rs    = 0;
    const size_t off_cur   = ((size_t)(N_NODES + 1) * 4 + 15) & ~(size_t)15;
    const size_t off_alloc = off_cur + (size_t)N_NODES * 4;
    const size_t off_csr   = off_alloc + 512;
    const size_t off_bsum  = off_csr + (size_t)N_EDGES * 4;
    const size_t off_flag  = off_bsum + (((size_t)NB_SCAN * 4 + 15) & ~(size_t)15);
    const size_t off_wp    = (off_flag + 16 + 255) & ~(size_t)255;
    const size_t off_X     = (off_wp + 64 * 64 * 16 + 255) & ~(size_t)255;
    const size_t need_mid  = off_X + (size_t)X_ROWS * 64 * sizeof(unsigned);
    const size_t off_Hb    = (need_mid + 255) & ~(size_t)255;
    const size_t need_full = off_Hb + (size_t)N_NODES * (D_IN / 2) * sizeof(unsigned);
    const size_t off_bin   = (need_full + 255) & ~(size_t)255;
    const size_t need_sort = off_bin + (size_t)NBUCK * BCAP * 4;

    int* row_start = (int*)((char*)d_ws + off_rs);
    int* cursor    = (int*)((char*)d_ws + off_cur);
    int* balloc    = (int*)((char*)d_ws + off_alloc);
    int* csr_pack  = (int*)((char*)d_ws + off_csr);
    int* bsum      = (int*)((char*)d_ws + off_bsum);
    int* flag      = (int*)((char*)d_ws + off_flag);
    unsigned short* Wp = (unsigned short*)((char*)d_ws + off_wp);
    unsigned* Xg   = (unsigned*)((char*)d_ws + off_X);
    unsigned* Hb   = (unsigned*)((char*)d_ws + off_Hb);
    int* binned    = (int*)((char*)d_ws + off_bin);

    detect_idx64_kernel<<<1, 128, 0, stream>>>((const int*)edge, flag, balloc);

    const int edge_blocks = (N_EDGES + 255) / 256;

    if (ws_size >= need_sort) {
        // main path: 5 dispatches
        prep_kernel<<<PACK_BLOCKS + CVT_BLOCKS + BIN_BLOCKS, 256, 0, stream>>>(
            Wm, Wp, H, Hb, edge, flag, balloc, binned);
        bucket_fill_scan_kernel<<<NBUCK, 1024, 0, stream>>>(
            balloc, binned, row_start, csr_pack);
        gather_bf16_kernel<<<G_TILES, 256, 0, stream>>>(
            H, Hb, row_start, csr_pack, Xg);
        gemm_mfma_kernel<<<N_TILES, 256, 0, stream>>>(Xg, Wp, out);
    } else {
        hipMemsetAsync(cursor, 0, (size_t)N_NODES * 4 + 512, stream);
        hist_kernel<<<edge_blocks, 256, 0, stream>>>(edge, flag, cursor);
        block_sum_kernel<<<NB_SCAN, 256, 0, stream>>>(cursor, bsum);
        scan_bsum_kernel<<<1, 512, 0, stream>>>(bsum, row_start);
        scan_counts_kernel<<<NB_SCAN, 256, 0, stream>>>(cursor, bsum, row_start);
        fill_kernel<<<edge_blocks, 256, 0, stream>>>(edge, flag, cursor, csr_pack);
        fused_gather_gemm_relu_kernel<<<N_TILES, 256, 0, stream>>>(
            H, row_start, csr_pack, Wm, out);
    }
}